// Round 5
// baseline (794.412 us; speedup 1.0000x reference)
//
#include <hip/hip_runtime.h>
#include <hip/hip_bf16.h>

#define TDIM 1024
#define NEXP 8
#define NHID 4096

typedef __hip_bfloat16 bf16;
typedef __attribute__((ext_vector_type(8))) short bf16x8;
typedef __attribute__((ext_vector_type(8))) unsigned short u16x8;
typedef __attribute__((ext_vector_type(4))) float f32x4;

__device__ __forceinline__ void gload_lds16(void* lds, const void* g) {
  __builtin_amdgcn_global_load_lds(
      (const __attribute__((address_space(1))) unsigned int*)g,
      (__attribute__((address_space(3))) unsigned int*)lds, 16, 0, 0);
}

__device__ __forceinline__ unsigned short f2bf_bits(float f) {
  __hip_bfloat16 b = __float2bfloat16(f);
  unsigned short u;
  __builtin_memcpy(&u, &b, 2);
  return u;
}

__device__ __forceinline__ float bf2f(unsigned short u) {
  union { unsigned int i; float f; } c;
  c.i = ((unsigned int)u) << 16;
  return c.f;
}

// ---------------- prep: k-octet-blocked weight convert + x cvt + router ----------------
// Weight convert: in [E][K][N] f32 -> out chunk c=( (e*(K/8)+kq)*N + n ): 8 bf16 = col n,
// k = kq*8..+8.  Lane reads 8 rows at same col (256B dense per row across wave), writes one
// dense 16B chunk (consecutive threads -> consecutive chunks). No LDS, no barrier.
__device__ __forceinline__ void cvt_chunk(const float* __restrict__ src, bf16* __restrict__ dst,
                                          int c, int kqShift, int nMask, int rowLen) {
  const int kq = c >> kqShift;  // includes e: (e*(K/8)+kq)
  const int n = c & nMask;
  const float* s = src + ((size_t)kq * 8) * rowLen + n;
  u16x8 o;
#pragma unroll
  for (int j = 0; j < 8; ++j) o[j] = f2bf_bits(s[(size_t)j * rowLen]);
  *reinterpret_cast<u16x8*>(dst + (size_t)c * 8) = o;
}

// blocks [0,8192): weight chunks (4 per thread); [8192,10240): router + x->bf16
__global__ __launch_bounds__(256) void prep_kernel(
    const float* __restrict__ W1, bf16* __restrict__ W1C, const float* __restrict__ W2,
    bf16* __restrict__ W2C, const float* __restrict__ x, bf16* __restrict__ xb,
    const float* __restrict__ Wr, int* __restrict__ idx, float* __restrict__ wtok,
    int* __restrict__ cnt, int T) {
  const int pb = blockIdx.x;
  const int tid = threadIdx.x;
  if (pb < 8192) {
    const int id = pb * 256 + tid;  // [0, 2M)
    // j=0,1 -> W1 chunks id, id+2M   (W1: K=1024,N=4096: kqShift=12, nMask=4095, rowLen=4096)
    cvt_chunk(W1, W1C, id, 12, 4095, 4096);
    cvt_chunk(W1, W1C, id + (1 << 21), 12, 4095, 4096);
    // j=2,3 -> W2 chunks id, id+2M   (W2: K=4096,N=1024: kqShift=10, nMask=1023, rowLen=1024)
    cvt_chunk(W2, W2C, id, 10, 1023, 1024);
    cvt_chunk(W2, W2C, id + (1 << 21), 10, 1023, 1024);
  } else {
    const int p = pb - 8192;
    const int wave = p * 4 + (tid >> 6);
    const int lane = tid & 63;
    if (wave >= T) return;
    const float4* xr4 = reinterpret_cast<const float4*>(x + (size_t)wave * TDIM);
    bf16* xbrow = xb + (size_t)wave * TDIM;
    float acc[NEXP];
#pragma unroll
    for (int e = 0; e < NEXP; ++e) acc[e] = 0.f;
    const float4* wr4 = reinterpret_cast<const float4*>(Wr);
#pragma unroll
    for (int i = 0; i < TDIM / 256; ++i) {
      float4 xv = xr4[lane + i * 64];
      ushort4 o;
      o.x = f2bf_bits(xv.x);
      o.y = f2bf_bits(xv.y);
      o.z = f2bf_bits(xv.z);
      o.w = f2bf_bits(xv.w);
      *reinterpret_cast<ushort4*>(xbrow + (lane + i * 64) * 4) = o;
      int row = (lane + i * 64) * 4;
#pragma unroll
      for (int j = 0; j < 4; ++j) {
        float xs = (&xv.x)[j];
        float4 wa = wr4[(row + j) * 2];
        float4 wb = wr4[(row + j) * 2 + 1];
        acc[0] += xs * wa.x;
        acc[1] += xs * wa.y;
        acc[2] += xs * wa.z;
        acc[3] += xs * wa.w;
        acc[4] += xs * wb.x;
        acc[5] += xs * wb.y;
        acc[6] += xs * wb.z;
        acc[7] += xs * wb.w;
      }
    }
#pragma unroll
    for (int e = 0; e < NEXP; ++e) {
      float v = acc[e];
#pragma unroll
      for (int s = 32; s; s >>= 1) v += __shfl_xor(v, s);
      acc[e] = v;
    }
    if (lane == 0) {
      int e0 = 0;
      float l0 = acc[0];
      for (int e = 1; e < NEXP; ++e)
        if (acc[e] > l0) { l0 = acc[e]; e0 = e; }
      int e1 = -1;
      float l1 = -INFINITY;
      for (int e = 0; e < NEXP; ++e)
        if (e != e0 && acc[e] > l1) { l1 = acc[e]; e1 = e; }
      float z = __expf(l1 - l0);
      idx[wave * 2] = e0;
      idx[wave * 2 + 1] = e1;
      wtok[wave * 2] = 1.f / (1.f + z);
      wtok[wave * 2 + 1] = z / (1.f + z);
      atomicAdd(&cnt[e0], 1);
      atomicAdd(&cnt[e1], 1);
    }
  }
}

__global__ void scan_kernel(const int* __restrict__ cnt, int* __restrict__ offs) {
  if (threadIdx.x == 0 && blockIdx.x == 0) {
    int s = 0;
    for (int e = 0; e < NEXP; ++e) { offs[e] = s; s += cnt[e]; }
  }
}

__global__ void build_perm_kernel(const int* __restrict__ idx, const int* __restrict__ offs,
                                  int* __restrict__ fill, int* __restrict__ perm,
                                  int* __restrict__ islot, int T) {
  int t = blockIdx.x * blockDim.x + threadIdx.x;
  if (t >= T) return;
#pragma unroll
  for (int k = 0; k < 2; ++k) {
    int e = idx[t * 2 + k];
    int p = offs[e] + atomicAdd(&fill[e], 1);
    perm[p] = t;
    islot[t * 2 + k] = p;
  }
}

// ---------------- grouped GEMM: 256x256x64, 8-phase, counted vmcnt, T2 swizzle ----------------
// B is k-octet-blocked [E][KD/8][ND][8] bf16: lane chunk (n, kslot_src) at
// ((kslot_src + k0/8)*ND + n)*8 -> kslot_src goes in the base, per-tile advance = k0*ND elems.
// LDS image identical to the [N][K] version, so schedule/swizzle unchanged.
template <int KD, int ND, bool GATHER, bool GELU>
__global__ __launch_bounds__(512, 2) void moe_gemm8(
    const bf16* __restrict__ A, const bf16* __restrict__ BC, const float* __restrict__ bias,
    const int* __restrict__ perm, const int* __restrict__ cnt, const int* __restrict__ offs,
    bf16* __restrict__ Dst, int nm, int nn) {
  __shared__ short lds[65536];  // 128 KiB: buf*32768 + op*16384 + half*8192 (shorts)

  const int nwg = NEXP * nm * nn;
  const int bid = blockIdx.x;
  const int wg = (bid & 7) * (nwg >> 3) + (bid >> 3);  // bijective: nwg % 8 == 0
  const int e = wg / (nm * nn);
  const int rem = wg % (nm * nn);
  const int mb = rem / nn, nb = rem % nn;

  const int ce = cnt[e];
  const int m0 = mb * 256;
  if (m0 >= ce) return;
  const int base = offs[e];
  const int n0 = nb * 256;
  const int tid = threadIdx.x;
  const int lane = tid & 63;
  const int wid = tid >> 6;
  const int wm = wid >> 2, wn = wid & 3;
  const int lcol = lane & 15;
  const int lkg = (lane >> 4) * 8;

  // per-lane swizzled k offsets (shorts) for fragment reads
  const int kxs0 = ((lkg << 1) ^ ((lcol & 7) << 4)) >> 1;
  const int kxs1 = (((lkg + 32) << 1) ^ ((lcol & 7) << 4)) >> 1;
  int aRow[4], bRow[2];
#pragma unroll
  for (int mm = 0; mm < 4; ++mm) aRow[mm] = (wm * 64 + mm * 16 + lcol) << 6;
#pragma unroll
  for (int n2 = 0; n2 < 2; ++n2) bRow[n2] = (wn * 32 + n2 * 16 + lcol) << 6;

  // staging: slot s = tid + i*512 -> row s>>3 (0..127), kslot s&7; source kslot_src = kslot^(row&7)
  const bf16* aP[2][2];
  const bf16* bP[2][2];
#pragma unroll
  for (int h = 0; h < 2; ++h)
#pragma unroll
    for (int i = 0; i < 2; ++i) {
      int s = tid + i * 512;
      int srow = s >> 3;
      int ksrc = (s & 7) ^ (srow & 7);
      int grow = m0 + h * 128 + srow;
      if (grow > ce - 1) grow = ce - 1;
      size_t arow = GATHER ? (size_t)perm[base + grow] : (size_t)(base + grow);
      aP[h][i] = A + arow * KD + ksrc * 8;
      bP[h][i] = BC + (size_t)e * KD * ND + ((size_t)ksrc * ND + (n0 + h * 128 + srow)) * 8;
    }

  f32x4 acc[8][4];
#pragma unroll
  for (int m = 0; m < 8; ++m)
#pragma unroll
    for (int n = 0; n < 4; ++n) acc[m][n] = (f32x4){0.f, 0.f, 0.f, 0.f};

  bf16x8 fA[4][2], fB[2][2];  // persist across phases (all indexing compile-time)

#define STAGE(SBUF, OP, HF, kA, kB)                                                  \
  {                                                                                  \
    char* sd = (char*)lds + (SBUF) * 65536 + (OP) * 32768 + (HF) * 16384 + tid * 16; \
    if (OP) {                                                                        \
      gload_lds16(sd, bP[HF][0] + (kB));                                             \
      gload_lds16(sd + 8192, bP[HF][1] + (kB));                                      \
    } else {                                                                         \
      gload_lds16(sd, aP[HF][0] + (kA));                                             \
      gload_lds16(sd + 8192, aP[HF][1] + (kA));                                      \
    }                                                                                \
  }

// QM,QN: quadrant; RA/RB: read fresh A/B fragments (else reuse registers);
// SOP,SHF: staged (op,half); SBUF: stage buffer; CBUF: consume buffer.
#define PHASE(QM, QN, RA, RB, SOP, SHF, SBUF, CBUF, kA, kB, DO_VM)                   \
  {                                                                                  \
    STAGE(SBUF, SOP, SHF, kA, kB);                                                   \
    if (DO_VM) asm volatile("s_waitcnt vmcnt(6)" ::: "memory");                      \
    __builtin_amdgcn_s_barrier();                                                    \
    asm volatile("" ::: "memory");                                                   \
    if (RA) {                                                                        \
      const short* Ab = lds + (CBUF) * 32768 + (QM) * 8192;                          \
      _Pragma("unroll") for (int mm = 0; mm < 4; ++mm) {                             \
        fA[mm][0] = *(const bf16x8*)(Ab + aRow[mm] + kxs0);                          \
        fA[mm][1] = *(const bf16x8*)(Ab + aRow[mm] + kxs1);                          \
      }                                                                              \
    }                                                                                \
    if (RB) {                                                                        \
      const short* Bb = lds + (CBUF) * 32768 + 16384 + (QN) * 8192;                  \
      _Pragma("unroll") for (int n2 = 0; n2 < 2; ++n2) {                             \
        fB[n2][0] = *(const bf16x8*)(Bb + bRow[n2] + kxs0);                          \
        fB[n2][1] = *(const bf16x8*)(Bb + bRow[n2] + kxs1);                          \
      }                                                                              \
    }                                                                                \
    asm volatile("s_waitcnt lgkmcnt(0)" ::: "memory");                               \
    __builtin_amdgcn_s_setprio(1);                                                   \
    _Pragma("unroll") for (int mm = 0; mm < 4; ++mm)                                 \
        _Pragma("unroll") for (int n2 = 0; n2 < 2; ++n2) {                           \
      acc[(QM) * 4 + mm][(QN) * 2 + n2] = __builtin_amdgcn_mfma_f32_16x16x32_bf16(   \
          fA[mm][0], fB[n2][0], acc[(QM) * 4 + mm][(QN) * 2 + n2], 0, 0, 0);         \
      acc[(QM) * 4 + mm][(QN) * 2 + n2] = __builtin_amdgcn_mfma_f32_16x16x32_bf16(   \
          fA[mm][1], fB[n2][1], acc[(QM) * 4 + mm][(QN) * 2 + n2], 0, 0, 0);         \
    }                                                                                \
    __builtin_amdgcn_s_setprio(0);                                                   \
  }

  // prologue: tile 0 -> buf0, in need-order A0,B0,A1,B1
  STAGE(0, 0, 0, 0, 0);
  STAGE(0, 1, 0, 0, 0);
  STAGE(0, 0, 1, 0, 0);
  STAGE(0, 1, 1, 0, 0);

  const int NI = KD / 128;
  for (int itv = 0; itv < NI; ++itv) {
    const int k1 = itv * 128 + 64;  // tile 2it+1 -> buf1 (consumed ph4-7)
    int k2 = itv * 128 + 128;       // tile 2it+2 -> buf0 (consumed next iter)
    if (k2 >= KD) k2 = 0;           // last iter: dummy restage (never consumed, keeps vmcnt math)
    const int k1B = k1 * ND, k2B = k2 * ND;
    PHASE(0, 0, 1, 1, 0, 0, 1, 0, k1, k1B, 1)
    PHASE(1, 0, 1, 0, 1, 0, 1, 0, k1, k1B, 1)
    PHASE(1, 1, 0, 1, 0, 1, 1, 0, k1, k1B, 1)
    PHASE(0, 1, 1, 0, 1, 1, 1, 0, k1, k1B, 0)
    PHASE(0, 0, 1, 1, 0, 0, 0, 1, k2, k2B, 1)
    PHASE(1, 0, 1, 0, 1, 0, 0, 1, k2, k2B, 1)
    PHASE(1, 1, 0, 1, 0, 1, 0, 1, k2, k2B, 1)
    PHASE(0, 1, 1, 0, 1, 1, 0, 1, k2, k2B, 0)
  }
#undef PHASE
#undef STAGE

  // epilogue: row = m0 + QM*128 + wm*64 + mm*16 + (lane>>4)*4 + r ;
  //           col = n0 + QN*128 + wn*32 + n2*16 + lcol
  float bv[4];
#pragma unroll
  for (int ni = 0; ni < 4; ++ni)
    bv[ni] = bias[e * ND + n0 + (ni >> 1) * 128 + wn * 32 + (ni & 1) * 16 + lcol];
  const int lr4 = (lane >> 4) * 4;
#pragma unroll
  for (int mi = 0; mi < 8; ++mi) {
    const int rbase = m0 + (mi >> 2) * 128 + wm * 64 + (mi & 3) * 16 + lr4;
#pragma unroll
    for (int r = 0; r < 4; ++r) {
      int grow = rbase + r;
      if (grow < ce) {
        bf16* drow = Dst + (size_t)(base + grow) * ND;
#pragma unroll
        for (int ni = 0; ni < 4; ++ni) {
          int col = n0 + (ni >> 1) * 128 + wn * 32 + (ni & 1) * 16 + lcol;
          float v = acc[mi][ni][r] + bv[ni];
          if (GELU) v = 0.5f * v * (1.0f + erff(v * 0.70710678118654752f));
          drow[col] = __float2bfloat16(v);
        }
      }
    }
  }
}

// ---------------- combine: out[t] = w0*y[slot0] + w1*y[slot1] ----------------
__global__ void combine_kernel(const bf16* __restrict__ y, const int* __restrict__ islot,
                               const float* __restrict__ wtok, float* __restrict__ out) {
  const int t = blockIdx.x;
  const int d = threadIdx.x * 4;
  const int s0 = islot[t * 2], s1 = islot[t * 2 + 1];
  const float w0 = wtok[t * 2], w1 = wtok[t * 2 + 1];
  ushort4 ya = *reinterpret_cast<const ushort4*>(y + (size_t)s0 * TDIM + d);
  ushort4 yb = *reinterpret_cast<const ushort4*>(y + (size_t)s1 * TDIM + d);
  float4 o;
  o.x = w0 * bf2f(ya.x) + w1 * bf2f(yb.x);
  o.y = w0 * bf2f(ya.y) + w1 * bf2f(yb.y);
  o.z = w0 * bf2f(ya.z) + w1 * bf2f(yb.z);
  o.w = w0 * bf2f(ya.w) + w1 * bf2f(yb.w);
  *reinterpret_cast<float4*>(out + (size_t)t * TDIM + d) = o;
}

extern "C" void kernel_launch(void* const* d_in, const int* in_sizes, int n_in, void* d_out,
                              int out_size, void* d_ws, size_t ws_size, hipStream_t stream) {
  const float* x = (const float*)d_in[0];
  const float* Wr = (const float*)d_in[1];
  const float* W1 = (const float*)d_in[2];
  const float* b1 = (const float*)d_in[3];
  const float* W2 = (const float*)d_in[4];
  const float* b2 = (const float*)d_in[5];
  float* out = (float*)d_out;
  const int T = in_sizes[0] / TDIM;  // 8192

  size_t off = 0;
  auto alloc = [&](size_t bytes) {
    void* q = (char*)d_ws + off;
    off += (bytes + 255) & ~(size_t)255;
    return q;
  };
  bf16* xb = (bf16*)alloc((size_t)T * TDIM * 2);
  bf16* W1C = (bf16*)alloc((size_t)NEXP * TDIM * NHID * 2);
  bf16* W2C = (bf16*)alloc((size_t)NEXP * TDIM * NHID * 2);
  bf16* h = (bf16*)alloc((size_t)2 * T * NHID * 2);
  int* idx = (int*)alloc((size_t)T * 2 * 4);
  float* wtok = (float*)alloc((size_t)T * 2 * 4);
  int* perm = (int*)alloc((size_t)T * 2 * 4);
  int* islot = (int*)alloc((size_t)T * 2 * 4);
  int* cnt = (int*)alloc(256);  // cnt[8] | fill[8] | offs[8]
  int* fill = cnt + 8;
  int* offs = cnt + 16;
  // y (32 MB bf16) aliases W1C (64 MB): W1C dead after GEMM1; y written by GEMM2, read by combine.
  bf16* y = W1C;

  hipMemsetAsync(cnt, 0, 64, stream);  // cnt + fill

  prep_kernel<<<10240, 256, 0, stream>>>(W1, W1C, W2, W2C, x, xb, Wr, idx, wtok, cnt, T);
  scan_kernel<<<1, 64, 0, stream>>>(cnt, offs);
  build_perm_kernel<<<(T + 255) / 256, 256, 0, stream>>>(idx, offs, fill, perm, islot, T);

  // GEMM1: h[slot] = gelu(x[perm[slot]] @ W1[e] + b1[e]); worst case 8192 rows/expert
  moe_gemm8<TDIM, NHID, true, true><<<NEXP * 32 * 16, 512, 0, stream>>>(
      xb, W1C, b1, perm, cnt, offs, h, 32, 16);
  // GEMM2: y[slot] = h[slot] @ W2[e] + b2[e]
  moe_gemm8<NHID, TDIM, false, false><<<NEXP * 32 * 4, 512, 0, stream>>>(
      h, W2C, b2, perm, cnt, offs, y, 32, 4);

  combine_kernel<<<T, 256, 0, stream>>>(y, islot, wtok, out);
}

// Round 6
// 775.163 us; speedup vs baseline: 1.0248x; 1.0248x over previous
//
#include <hip/hip_runtime.h>
#include <hip/hip_bf16.h>

#define TDIM 1024
#define NEXP 8
#define NHID 4096

typedef __hip_bfloat16 bf16;
typedef __attribute__((ext_vector_type(8))) short bf16x8;
typedef __attribute__((ext_vector_type(8))) unsigned short u16x8;
typedef __attribute__((ext_vector_type(4))) float f32x4;

__device__ __forceinline__ void gload_lds16(void* lds, const void* g) {
  __builtin_amdgcn_global_load_lds(
      (const __attribute__((address_space(1))) unsigned int*)g,
      (__attribute__((address_space(3))) unsigned int*)lds, 16, 0, 0);
}

__device__ __forceinline__ unsigned short f2bf_bits(float f) {
  __hip_bfloat16 b = __float2bfloat16(f);
  unsigned short u;
  __builtin_memcpy(&u, &b, 2);
  return u;
}

__device__ __forceinline__ float bf2f(unsigned short u) {
  union { unsigned int i; float f; } c;
  c.i = ((unsigned int)u) << 16;
  return c.f;
}

// k-octet-blocked weight convert: in [E][K][N] f32 -> chunk c = (e*(K/8)+kq)*N + n holds
// 8 bf16 {W[kq*8+j][n]}. Lane reads 8 rows at same col (dword, dense across wave), writes one
// dense 16B chunk (consecutive threads -> consecutive chunks). No LDS, no barrier.
__device__ __forceinline__ void cvt_chunk(const float* __restrict__ src, bf16* __restrict__ dst,
                                          int c, int kqShift, int nMask, int rowLen) {
  const int kq = c >> kqShift;  // includes e
  const int n = c & nMask;
  const float* s = src + ((size_t)kq * 8) * rowLen + n;
  u16x8 o;
#pragma unroll
  for (int j = 0; j < 8; ++j) o[j] = f2bf_bits(s[(size_t)j * rowLen]);
  *reinterpret_cast<u16x8*>(dst + (size_t)c * 8) = o;
}

// ---------------- prep: W1 convert + router(+x->bf16) ----------------
// blocks [0,4096): W1 chunks (4/thread); [4096,6144): router + x->bf16 (4 token-waves/block)
__global__ __launch_bounds__(256) void prep_kernel(
    const float* __restrict__ W1, bf16* __restrict__ W1C, const float* __restrict__ x,
    bf16* __restrict__ xb, const float* __restrict__ Wr, int* __restrict__ idx,
    float* __restrict__ wtok, int* __restrict__ cnt, int T) {
  __shared__ float xs[4][1024];
  const int pb = blockIdx.x;
  const int tid = threadIdx.x;
  if (pb < 4096) {
    const int id = pb * 256 + tid;  // [0, 1M)
#pragma unroll
    for (int v = 0; v < 4; ++v) cvt_chunk(W1, W1C, id + v * (1 << 20), 12, 4095, 4096);
  } else {
    const int p = pb - 4096;
    const int wave = p * 4 + (tid >> 6);
    const int lane = tid & 63;
    if (wave >= T) return;
    float* xrow = xs[tid >> 6];
    const float4* xr4 = reinterpret_cast<const float4*>(x + (size_t)wave * TDIM);
    bf16* xbrow = xb + (size_t)wave * TDIM;
    // pass 1: float4 loads -> xb (bf16) + LDS stage
#pragma unroll
    for (int i = 0; i < TDIM / 256; ++i) {
      float4 xv = xr4[lane + i * 64];
      ushort4 o;
      o.x = f2bf_bits(xv.x);
      o.y = f2bf_bits(xv.y);
      o.z = f2bf_bits(xv.z);
      o.w = f2bf_bits(xv.w);
      *reinterpret_cast<ushort4*>(xbrow + (lane + i * 64) * 4) = o;
      *reinterpret_cast<float4*>(&xrow[(lane + i * 64) * 4]) = xv;
    }
    // pass 2: scalar x from LDS (conflict-free), Wr rows coalesced (32B/lane dense)
    float acc[NEXP];
#pragma unroll
    for (int e = 0; e < NEXP; ++e) acc[e] = 0.f;
    const float4* wr4 = reinterpret_cast<const float4*>(Wr);
#pragma unroll
    for (int i = 0; i < TDIM / 64; ++i) {
      float xv = xrow[lane + i * 64];
      float4 wa = wr4[(lane + i * 64) * 2];
      float4 wb = wr4[(lane + i * 64) * 2 + 1];
      acc[0] += xv * wa.x;
      acc[1] += xv * wa.y;
      acc[2] += xv * wa.z;
      acc[3] += xv * wa.w;
      acc[4] += xv * wb.x;
      acc[5] += xv * wb.y;
      acc[6] += xv * wb.z;
      acc[7] += xv * wb.w;
    }
#pragma unroll
    for (int e = 0; e < NEXP; ++e) {
      float v = acc[e];
#pragma unroll
      for (int s = 32; s; s >>= 1) v += __shfl_xor(v, s);
      acc[e] = v;
    }
    if (lane == 0) {
      int e0 = 0;
      float l0 = acc[0];
      for (int e = 1; e < NEXP; ++e)
        if (acc[e] > l0) { l0 = acc[e]; e0 = e; }
      int e1 = -1;
      float l1 = -INFINITY;
      for (int e = 0; e < NEXP; ++e)
        if (e != e0 && acc[e] > l1) { l1 = acc[e]; e1 = e; }
      float z = __expf(l1 - l0);
      idx[wave * 2] = e0;
      idx[wave * 2 + 1] = e1;
      wtok[wave * 2] = 1.f / (1.f + z);
      wtok[wave * 2 + 1] = z / (1.f + z);
      atomicAdd(&cnt[e0], 1);
      atomicAdd(&cnt[e1], 1);
    }
  }
}

__global__ void scan_kernel(const int* __restrict__ cnt, int* __restrict__ offs) {
  if (threadIdx.x == 0 && blockIdx.x == 0) {
    int s = 0;
    for (int e = 0; e < NEXP; ++e) { offs[e] = s; s += cnt[e]; }
  }
}

__global__ void build_perm_kernel(const int* __restrict__ idx, const int* __restrict__ offs,
                                  int* __restrict__ fill, int* __restrict__ perm,
                                  int* __restrict__ islot, int T) {
  int t = blockIdx.x * blockDim.x + threadIdx.x;
  if (t >= T) return;
#pragma unroll
  for (int k = 0; k < 2; ++k) {
    int e = idx[t * 2 + k];
    int p = offs[e] + atomicAdd(&fill[e], 1);
    perm[p] = t;
    islot[t * 2 + k] = p;
  }
}

// ---------------- grouped GEMM: 256x256x64, 8-phase, counted vmcnt, T2 swizzle ----------------
// B is k-octet-blocked [E][KD/8][ND][8] bf16. LDS image identical to the [N][K] version.
// CONV: blocks beyond the GEMM grid stream-convert W2 (overlaps GEMM1 compute; W2C is
// only consumed by GEMM2, enqueued later on the same stream).
template <int KD, int ND, bool GATHER, bool GELU, bool CONV>
__global__ __launch_bounds__(512, 2) void moe_gemm8(
    const bf16* __restrict__ A, const bf16* __restrict__ BC, const float* __restrict__ bias,
    const int* __restrict__ perm, const int* __restrict__ cnt, const int* __restrict__ offs,
    bf16* __restrict__ Dst, int nm, int nn, const float* __restrict__ Wsrc,
    bf16* __restrict__ Wdst) {
  __shared__ short lds[65536];  // 128 KiB: buf*32768 + op*16384 + half*8192 (shorts)

  const int nwg = NEXP * nm * nn;
  const int bid = blockIdx.x;
  if (CONV && bid >= nwg) {
    const int id = (bid - nwg) * 512 + threadIdx.x;  // [0, 512K)
#pragma unroll
    for (int v = 0; v < 8; ++v) cvt_chunk(Wsrc, Wdst, id + v * (1 << 19), 10, 1023, 1024);
    return;
  }
  const int wg = (bid & 7) * (nwg >> 3) + (bid >> 3);  // bijective: nwg % 8 == 0
  const int e = wg / (nm * nn);
  const int rem = wg % (nm * nn);
  const int mb = rem / nn, nb = rem % nn;

  const int ce = cnt[e];
  const int m0 = mb * 256;
  if (m0 >= ce) return;
  const int base = offs[e];
  const int n0 = nb * 256;
  const int tid = threadIdx.x;
  const int lane = tid & 63;
  const int wid = tid >> 6;
  const int wm = wid >> 2, wn = wid & 3;
  const int lcol = lane & 15;
  const int lkg = (lane >> 4) * 8;

  // per-lane swizzled k offsets (shorts) for fragment reads
  const int kxs0 = ((lkg << 1) ^ ((lcol & 7) << 4)) >> 1;
  const int kxs1 = (((lkg + 32) << 1) ^ ((lcol & 7) << 4)) >> 1;
  int aRow[4], bRow[2];
#pragma unroll
  for (int mm = 0; mm < 4; ++mm) aRow[mm] = (wm * 64 + mm * 16 + lcol) << 6;
#pragma unroll
  for (int n2 = 0; n2 < 2; ++n2) bRow[n2] = (wn * 32 + n2 * 16 + lcol) << 6;

  // staging: slot s = tid + i*512 -> row s>>3 (0..127), kslot s&7; source kslot_src = kslot^(row&7)
  const bf16* aP[2][2];
  const bf16* bP[2][2];
#pragma unroll
  for (int h = 0; h < 2; ++h)
#pragma unroll
    for (int i = 0; i < 2; ++i) {
      int s = tid + i * 512;
      int srow = s >> 3;
      int ksrc = (s & 7) ^ (srow & 7);
      int grow = m0 + h * 128 + srow;
      if (grow > ce - 1) grow = ce - 1;
      size_t arow = GATHER ? (size_t)perm[base + grow] : (size_t)(base + grow);
      aP[h][i] = A + arow * KD + ksrc * 8;
      bP[h][i] = BC + (size_t)e * KD * ND + ((size_t)ksrc * ND + (n0 + h * 128 + srow)) * 8;
    }

  f32x4 acc[8][4];
#pragma unroll
  for (int m = 0; m < 8; ++m)
#pragma unroll
    for (int n = 0; n < 4; ++n) acc[m][n] = (f32x4){0.f, 0.f, 0.f, 0.f};

  bf16x8 fA[4][2], fB[2][2];  // persist across phases (all indexing compile-time)

#define STAGE(SBUF, OP, HF, kA, kB)                                                  \
  {                                                                                  \
    char* sd = (char*)lds + (SBUF) * 65536 + (OP) * 32768 + (HF) * 16384 + tid * 16; \
    if (OP) {                                                                        \
      gload_lds16(sd, bP[HF][0] + (kB));                                             \
      gload_lds16(sd + 8192, bP[HF][1] + (kB));                                      \
    } else {                                                                         \
      gload_lds16(sd, aP[HF][0] + (kA));                                             \
      gload_lds16(sd + 8192, aP[HF][1] + (kA));                                      \
    }                                                                                \
  }

// QM,QN: quadrant; RA/RB: read fresh A/B fragments (else reuse registers);
// SOP,SHF: staged (op,half); SBUF: stage buffer; CBUF: consume buffer.
#define PHASE(QM, QN, RA, RB, SOP, SHF, SBUF, CBUF, kA, kB, DO_VM)                   \
  {                                                                                  \
    STAGE(SBUF, SOP, SHF, kA, kB);                                                   \
    if (DO_VM) asm volatile("s_waitcnt vmcnt(6)" ::: "memory");                      \
    __builtin_amdgcn_s_barrier();                                                    \
    asm volatile("" ::: "memory");                                                   \
    if (RA) {                                                                        \
      const short* Ab = lds + (CBUF) * 32768 + (QM) * 8192;                          \
      _Pragma("unroll") for (int mm = 0; mm < 4; ++mm) {                             \
        fA[mm][0] = *(const bf16x8*)(Ab + aRow[mm] + kxs0);                          \
        fA[mm][1] = *(const bf16x8*)(Ab + aRow[mm] + kxs1);                          \
      }                                                                              \
    }                                                                                \
    if (RB) {                                                                        \
      const short* Bb = lds + (CBUF) * 32768 + 16384 + (QN) * 8192;                  \
      _Pragma("unroll") for (int n2 = 0; n2 < 2; ++n2) {                             \
        fB[n2][0] = *(const bf16x8*)(Bb + bRow[n2] + kxs0);                          \
        fB[n2][1] = *(const bf16x8*)(Bb + bRow[n2] + kxs1);                          \
      }                                                                              \
    }                                                                                \
    asm volatile("s_waitcnt lgkmcnt(0)" ::: "memory");                               \
    __builtin_amdgcn_s_setprio(1);                                                   \
    _Pragma("unroll") for (int mm = 0; mm < 4; ++mm)                                 \
        _Pragma("unroll") for (int n2 = 0; n2 < 2; ++n2) {                           \
      acc[(QM) * 4 + mm][(QN) * 2 + n2] = __builtin_amdgcn_mfma_f32_16x16x32_bf16(   \
          fA[mm][0], fB[n2][0], acc[(QM) * 4 + mm][(QN) * 2 + n2], 0, 0, 0);         \
      acc[(QM) * 4 + mm][(QN) * 2 + n2] = __builtin_amdgcn_mfma_f32_16x16x32_bf16(   \
          fA[mm][1], fB[n2][1], acc[(QM) * 4 + mm][(QN) * 2 + n2], 0, 0, 0);         \
    }                                                                                \
    __builtin_amdgcn_s_setprio(0);                                                   \
  }

  // prologue: tile 0 -> buf0, in need-order A0,B0,A1,B1
  STAGE(0, 0, 0, 0, 0);
  STAGE(0, 1, 0, 0, 0);
  STAGE(0, 0, 1, 0, 0);
  STAGE(0, 1, 1, 0, 0);

  const int NI = KD / 128;
  for (int itv = 0; itv < NI; ++itv) {
    const int k1 = itv * 128 + 64;  // tile 2it+1 -> buf1 (consumed ph4-7)
    int k2 = itv * 128 + 128;       // tile 2it+2 -> buf0 (consumed next iter)
    if (k2 >= KD) k2 = 0;           // last iter: dummy restage (never consumed, keeps vmcnt math)
    const int k1B = k1 * ND, k2B = k2 * ND;
    PHASE(0, 0, 1, 1, 0, 0, 1, 0, k1, k1B, 1)
    PHASE(1, 0, 1, 0, 1, 0, 1, 0, k1, k1B, 1)
    PHASE(1, 1, 0, 1, 0, 1, 1, 0, k1, k1B, 1)
    PHASE(0, 1, 1, 0, 1, 1, 1, 0, k1, k1B, 0)
    PHASE(0, 0, 1, 1, 0, 0, 0, 1, k2, k2B, 1)
    PHASE(1, 0, 1, 0, 1, 0, 0, 1, k2, k2B, 1)
    PHASE(1, 1, 0, 1, 0, 1, 0, 1, k2, k2B, 1)
    PHASE(0, 1, 1, 0, 1, 1, 0, 1, k2, k2B, 0)
  }
#undef PHASE
#undef STAGE

  // epilogue: row = m0 + QM*128 + wm*64 + mm*16 + (lane>>4)*4 + r ;
  //           col = n0 + QN*128 + wn*32 + n2*16 + lcol
  float bv[4];
#pragma unroll
  for (int ni = 0; ni < 4; ++ni)
    bv[ni] = bias[e * ND + n0 + (ni >> 1) * 128 + wn * 32 + (ni & 1) * 16 + lcol];
  const int lr4 = (lane >> 4) * 4;
#pragma unroll
  for (int mi = 0; mi < 8; ++mi) {
    const int rbase = m0 + (mi >> 2) * 128 + wm * 64 + (mi & 3) * 16 + lr4;
#pragma unroll
    for (int r = 0; r < 4; ++r) {
      int grow = rbase + r;
      if (grow < ce) {
        bf16* drow = Dst + (size_t)(base + grow) * ND;
#pragma unroll
        for (int ni = 0; ni < 4; ++ni) {
          int col = n0 + (ni >> 1) * 128 + wn * 32 + (ni & 1) * 16 + lcol;
          float v = acc[mi][ni][r] + bv[ni];
          if (GELU) v = 0.5f * v * (1.0f + erff(v * 0.70710678118654752f));
          drow[col] = __float2bfloat16(v);
        }
      }
    }
  }
}

// ---------------- combine: out[t] = w0*y[slot0] + w1*y[slot1] ----------------
__global__ void combine_kernel(const bf16* __restrict__ y, const int* __restrict__ islot,
                               const float* __restrict__ wtok, float* __restrict__ out) {
  const int t = blockIdx.x;
  const int d = threadIdx.x * 4;
  const int s0 = islot[t * 2], s1 = islot[t * 2 + 1];
  const float w0 = wtok[t * 2], w1 = wtok[t * 2 + 1];
  ushort4 ya = *reinterpret_cast<const ushort4*>(y + (size_t)s0 * TDIM + d);
  ushort4 yb = *reinterpret_cast<const ushort4*>(y + (size_t)s1 * TDIM + d);
  float4 o;
  o.x = w0 * bf2f(ya.x) + w1 * bf2f(yb.x);
  o.y = w0 * bf2f(ya.y) + w1 * bf2f(yb.y);
  o.z = w0 * bf2f(ya.z) + w1 * bf2f(yb.z);
  o.w = w0 * bf2f(ya.w) + w1 * bf2f(yb.w);
  *reinterpret_cast<float4*>(out + (size_t)t * TDIM + d) = o;
}

extern "C" void kernel_launch(void* const* d_in, const int* in_sizes, int n_in, void* d_out,
                              int out_size, void* d_ws, size_t ws_size, hipStream_t stream) {
  const float* x = (const float*)d_in[0];
  const float* Wr = (const float*)d_in[1];
  const float* W1 = (const float*)d_in[2];
  const float* b1 = (const float*)d_in[3];
  const float* W2 = (const float*)d_in[4];
  const float* b2 = (const float*)d_in[5];
  float* out = (float*)d_out;
  const int T = in_sizes[0] / TDIM;  // 8192

  size_t off = 0;
  auto alloc = [&](size_t bytes) {
    void* q = (char*)d_ws + off;
    off += (bytes + 255) & ~(size_t)255;
    return q;
  };
  bf16* xb = (bf16*)alloc((size_t)T * TDIM * 2);
  bf16* W1C = (bf16*)alloc((size_t)NEXP * TDIM * NHID * 2);
  bf16* W2C = (bf16*)alloc((size_t)NEXP * TDIM * NHID * 2);
  bf16* h = (bf16*)alloc((size_t)2 * T * NHID * 2);
  int* idx = (int*)alloc((size_t)T * 2 * 4);
  float* wtok = (float*)alloc((size_t)T * 2 * 4);
  int* perm = (int*)alloc((size_t)T * 2 * 4);
  int* islot = (int*)alloc((size_t)T * 2 * 4);
  int* cnt = (int*)alloc(256);  // cnt[8] | fill[8] | offs[8]
  int* fill = cnt + 8;
  int* offs = cnt + 16;
  // y (32 MB bf16) aliases W1C (64 MB): W1C dead after GEMM1; y written by GEMM2, read by combine.
  bf16* y = W1C;

  hipMemsetAsync(cnt, 0, 64, stream);  // cnt + fill

  prep_kernel<<<6144, 256, 0, stream>>>(W1, W1C, x, xb, Wr, idx, wtok, cnt, T);
  scan_kernel<<<1, 64, 0, stream>>>(cnt, offs);
  build_perm_kernel<<<(T + 255) / 256, 256, 0, stream>>>(idx, offs, fill, perm, islot, T);

  // GEMM1 (+1024 appended blocks stream-converting W2 -> W2C, consumed only by GEMM2)
  moe_gemm8<TDIM, NHID, true, true, true><<<NEXP * 32 * 16 + 1024, 512, 0, stream>>>(
      xb, W1C, b1, perm, cnt, offs, h, 32, 16, W2, W2C);
  // GEMM2: y[slot] = h[slot] @ W2[e] + b2[e]
  moe_gemm8<NHID, TDIM, false, false, false><<<NEXP * 32 * 4, 512, 0, stream>>>(
      h, W2C, b2, perm, cnt, offs, y, 32, 4, nullptr, nullptr);

  combine_kernel<<<T, 256, 0, stream>>>(y, islot, wtok, out);
}